// Round 5
// baseline (915.074 us; speedup 1.0000x reference)
//
#include <hip/hip_runtime.h>

#define N_IN_CH 256
#define N_OUT_CH 64
#define BROWS 128          // rows per bucket
#define BSHIFT 7
#define NBMAX 1024         // padded bucket array (nbuck = 782)
#define EB 4096            // edges per binning chunk
#define XPAD 264
#define SCAN_BS 1024

typedef __attribute__((ext_vector_type(8))) short short8;
typedef __attribute__((ext_vector_type(4))) float f32x4;

__device__ inline ushort f2bf(float f) {
    unsigned u = __float_as_uint(f);
    return (ushort)((u + 0x7FFFu + ((u >> 16) & 1u)) >> 16);   // RTNE
}
__device__ inline float bf2f(ushort u) {
    return __uint_as_float(((unsigned)u) << 16);
}

// --- Kernel 1: W [64][256] fp32 -> bf16 ---
__global__ void wbf_kernel(const float* __restrict__ W, ushort* __restrict__ Wbf) {
    int i = blockIdx.x * blockDim.x + threadIdx.x;
    if (i < N_OUT_CH * N_IN_CH) Wbf[i] = f2bf(W[i]);
}

// --- Kernel 2: Xp = X @ W^T via bf16 MFMA; 64 rows/block, K=256 in one shot ---
__global__ __launch_bounds__(256) void mfma_gemm_kernel(const float* __restrict__ X,
        const ushort* __restrict__ Wbf, ushort* __restrict__ Xp, int nrows) {
    __shared__ ushort Xs[64 * XPAD];
    __shared__ ushort Ws[64 * XPAD];

    const int tid = threadIdx.x;
    const int row0 = blockIdx.x * 64;

    #pragma unroll
    for (int it = 0; it < 16; ++it) {
        int f = it * 256 + tid;
        int n = f >> 6, c4 = f & 63;
        ushort4 v = *(const ushort4*)&Wbf[n * N_IN_CH + c4 * 4];
        *(ushort4*)&Ws[n * XPAD + c4 * 4] = v;
    }
    #pragma unroll
    for (int it = 0; it < 16; ++it) {
        int f = it * 256 + tid;
        int r = f >> 6, c4 = f & 63;
        int gr = row0 + r;
        float4 x = make_float4(0.f, 0.f, 0.f, 0.f);
        if (gr < nrows) x = *(const float4*)&X[(size_t)gr * N_IN_CH + c4 * 4];
        ushort4 u;
        u.x = f2bf(x.x); u.y = f2bf(x.y); u.z = f2bf(x.z); u.w = f2bf(x.w);
        *(ushort4*)&Xs[r * XPAD + c4 * 4] = u;
    }
    __syncthreads();

    const int wave = tid >> 6, lane = tid & 63;
    const int ml = lane & 15, quad = lane >> 4;

    const ushort* abase = &Xs[(wave * 16 + ml) * XPAD + quad * 8];
    short8 a[8];
    #pragma unroll
    for (int kt = 0; kt < 8; ++kt) a[kt] = *(const short8*)&abase[kt * 32];

    const ushort* bbase = &Ws[ml * XPAD + quad * 8];

    #pragma unroll
    for (int nt = 0; nt < 4; ++nt) {
        f32x4 acc = {0.f, 0.f, 0.f, 0.f};
        #pragma unroll
        for (int kt = 0; kt < 8; ++kt) {
            short8 b = *(const short8*)&bbase[nt * 16 * XPAD + kt * 32];
            acc = __builtin_amdgcn_mfma_f32_16x16x32_bf16(a[kt], b, acc, 0, 0, 0);
        }
        #pragma unroll
        for (int reg = 0; reg < 4; ++reg) {
            int gr = row0 + wave * 16 + quad * 4 + reg;
            if (gr < nrows)
                Xp[(size_t)gr * N_OUT_CH + nt * 16 + ml] = f2bf(acc[reg]);
        }
    }
}

// --- Bucket histogram: LDS-aggregated, one global atomicAdd per (WG,bucket) ---
__global__ __launch_bounds__(256) void bhist_kernel(const int* __restrict__ rows,
        int* __restrict__ gcnt, int nnz, int nbuck) {
    __shared__ int h[NBMAX];
    const int t = threadIdx.x;
    for (int i = t; i < NBMAX; i += 256) h[i] = 0;
    __syncthreads();
    const int e0 = blockIdx.x * EB;
    const int cnt = min(EB, nnz - e0);
    for (int i = t; i < cnt; i += 256)
        atomicAdd(&h[rows[e0 + i] >> BSHIFT], 1);
    __syncthreads();
    for (int b = t; b < nbuck; b += 256) {
        int c = h[b];
        if (c) atomicAdd(&gcnt[b], c);
    }
}

// --- Exclusive scan of bucket counts -> starts[] and cursor[] (working copy) ---
__global__ __launch_bounds__(SCAN_BS) void bscan_kernel(const int* __restrict__ gcnt,
        int* __restrict__ starts, int* __restrict__ cursor, int nbuck) {
    __shared__ int sh[NBMAX];
    int t = threadIdx.x;
    int v = (t < nbuck) ? gcnt[t] : 0;
    sh[t] = v;
    __syncthreads();
    for (int d = 1; d < NBMAX; d <<= 1) {
        int u = (t >= d) ? sh[t - d] : 0;
        __syncthreads();
        sh[t] += u;
        __syncthreads();
    }
    if (t < nbuck) { int ex = sh[t] - v; starts[t] = ex; cursor[t] = ex; }
}

// --- LDS-staged binning: group chunk's edges by bucket in LDS, flush dense runs ---
__global__ __launch_bounds__(256) void binning_kernel(const int* __restrict__ rows,
        const int* __restrict__ cols, const float* __restrict__ vals,
        int* __restrict__ cursor, int2* __restrict__ binned, int nnz, int nbuck) {
    __shared__ int hcnt[NBMAX];
    __shared__ int hstart[NBMAX];
    __shared__ int gbase[NBMAX];
    __shared__ int wsum[4];
    __shared__ int2 stage[EB];      // 32 KB
    __shared__ ushort sbid[EB];     // 8 KB

    const int t = threadIdx.x;
    const int e0 = blockIdx.x * EB;
    const int cnt = min(EB, nnz - e0);

    for (int i = t; i < NBMAX; i += 256) hcnt[i] = 0;
    __syncthreads();
    for (int i = t; i < cnt; i += 256)
        atomicAdd(&hcnt[rows[e0 + i] >> BSHIFT], 1);
    __syncthreads();

    // exclusive scan hcnt[0..1024) -> hstart (4 elems/thread + wave scan)
    {
        const int base = t * 4;
        int a0 = hcnt[base], a1 = hcnt[base + 1], a2 = hcnt[base + 2], a3 = hcnt[base + 3];
        int s = a0 + a1 + a2 + a3;
        const int lane = t & 63, w = t >> 6;
        int inc = s;
        #pragma unroll
        for (int d = 1; d < 64; d <<= 1) {
            int u = __shfl_up(inc, d, 64);
            if (lane >= d) inc += u;
        }
        if (lane == 63) wsum[w] = inc;
        __syncthreads();
        int woff = 0;
        #pragma unroll
        for (int i = 0; i < 4; ++i) if (i < w) woff += wsum[i];
        int ex = woff + inc - s;
        hstart[base]     = ex;
        hstart[base + 1] = ex + a0;
        hstart[base + 2] = ex + a0 + a1;
        hstart[base + 3] = ex + a0 + a1 + a2;
    }
    __syncthreads();

    // reserve global range per bucket; reset hcnt -> fill cursor
    for (int b = t; b < nbuck; b += 256) {
        int c = hcnt[b];
        gbase[b] = c ? atomicAdd(&cursor[b], c) : 0;
        hcnt[b] = 0;
    }
    __syncthreads();

    // scatter into LDS stage, grouped by bucket
    for (int i = t; i < cnt; i += 256) {
        int e = e0 + i;
        int r = rows[e];
        int c = cols[e];
        float v = vals[e];
        int b = r >> BSHIFT;
        int k = atomicAdd(&hcnt[b], 1);
        int pos = hstart[b] + k;
        stage[pos] = make_int2(((r & (BROWS - 1)) << 17) | c, __float_as_int(v));
        sbid[pos] = (ushort)b;
    }
    __syncthreads();

    // flush: consecutive i -> mostly-consecutive global dst (dense runs)
    for (int i = t; i < cnt; i += 256) {
        int b = sbid[i];
        binned[gbase[b] + (i - hstart[b])] = stage[i];
    }
}

// --- SpMM: one WG per bucket, fp32 LDS accumulator, no HBM atomics ---
__global__ __launch_bounds__(256) void spmm_bucket_kernel(const int* __restrict__ starts,
        const int* __restrict__ cursor, const int2* __restrict__ binned,
        const ushort* __restrict__ Xp, float* __restrict__ out, int nrows) {
    __shared__ float acc[BROWS * N_OUT_CH];   // 32 KB
    const int t = threadIdx.x;
    float4* accv = (float4*)acc;
    #pragma unroll
    for (int k = 0; k < 8; ++k)
        accv[t + k * 256] = make_float4(0.f, 0.f, 0.f, 0.f);
    __syncthreads();

    const int b = blockIdx.x;
    const int s = starts[b], e = cursor[b];   // cursor[b] == end after binning
    const int lane = t & 63, w = t >> 6;
    const int n = e - s;
    const int per = (n + 3) >> 2;
    int i = s + w * per;
    const int iend = min(i + per, e);

    for (; i + 4 <= iend; i += 4) {
        int2 E0 = binned[i], E1 = binned[i + 1], E2 = binned[i + 2], E3 = binned[i + 3];
        float x0 = bf2f(Xp[(size_t)(E0.x & 0x1FFFF) * N_OUT_CH + lane]);
        float x1 = bf2f(Xp[(size_t)(E1.x & 0x1FFFF) * N_OUT_CH + lane]);
        float x2 = bf2f(Xp[(size_t)(E2.x & 0x1FFFF) * N_OUT_CH + lane]);
        float x3 = bf2f(Xp[(size_t)(E3.x & 0x1FFFF) * N_OUT_CH + lane]);
        atomicAdd(&acc[(E0.x >> 17) * N_OUT_CH + lane], __int_as_float(E0.y) * x0);
        atomicAdd(&acc[(E1.x >> 17) * N_OUT_CH + lane], __int_as_float(E1.y) * x1);
        atomicAdd(&acc[(E2.x >> 17) * N_OUT_CH + lane], __int_as_float(E2.y) * x2);
        atomicAdd(&acc[(E3.x >> 17) * N_OUT_CH + lane], __int_as_float(E3.y) * x3);
    }
    for (; i < iend; ++i) {
        int2 E = binned[i];
        atomicAdd(&acc[(E.x >> 17) * N_OUT_CH + lane],
                  __int_as_float(E.y) * bf2f(Xp[(size_t)(E.x & 0x1FFFF) * N_OUT_CH + lane]));
    }
    __syncthreads();

    const int row0 = b << BSHIFT;
    float4* outv = (float4*)out + (size_t)row0 * (N_OUT_CH / 4);
    #pragma unroll
    for (int k = 0; k < 8; ++k) {
        int idx = t + k * 256;        // float4 index within block
        int r = idx >> 4;             // 16 float4 per row
        if (row0 + r < nrows) outv[idx] = accv[idx];
    }
}

// --- Fallback atomic SpMM (ws too small — not expected) ---
__global__ __launch_bounds__(256) void spmm_atomic_kernel(const int* __restrict__ rows,
        const int* __restrict__ cols, const float* __restrict__ vals,
        const ushort* __restrict__ Xp, float* __restrict__ out, int nnz) {
    int t = blockIdx.x * blockDim.x + threadIdx.x;
    int e = t >> 6;
    int c = t & 63;
    if (e < nnz) {
        atomicAdd(&out[(size_t)rows[e] * N_OUT_CH + c],
                  vals[e] * bf2f(Xp[(size_t)cols[e] * N_OUT_CH + c]));
    }
}

extern "C" void kernel_launch(void* const* d_in, const int* in_sizes, int n_in,
                              void* d_out, int out_size, void* d_ws, size_t ws_size,
                              hipStream_t stream) {
    const float* X      = (const float*)d_in[2];
    const float* W      = (const float*)d_in[3];
    const int*   L_rows = (const int*)d_in[4];
    const int*   L_cols = (const int*)d_in[5];
    const float* L_vals = (const float*)d_in[6];
    float* out = (float*)d_out;

    const int nrows = in_sizes[2] / N_IN_CH;   // 100000
    const int nnz   = in_sizes[4];             // 1600000

    const int nbuck   = (nrows + BROWS - 1) >> BSHIFT;   // 782
    const int nchunks = (nnz + EB - 1) / EB;             // 391

    // workspace layout (8B-aligned)
    size_t off_wbf = 0;                                         // 32 KB
    size_t off_xp  = 65536;
    size_t off_gc  = off_xp + (size_t)nrows * N_OUT_CH * 2;     // Xp bf16: 12.8 MB
    size_t off_st  = off_gc + (size_t)NBMAX * 4;
    size_t off_cu  = off_st + (size_t)NBMAX * 4;
    size_t off_bn  = off_cu + (size_t)NBMAX * 4;
    size_t need    = off_bn + (size_t)nnz * 8;                  // binned: 12.8 MB

    ushort* Wbf = (ushort*)((char*)d_ws + off_wbf);
    ushort* Xp  = (ushort*)((char*)d_ws + off_xp);

    wbf_kernel<<<(N_OUT_CH * N_IN_CH + 255) / 256, 256, 0, stream>>>(W, Wbf);
    mfma_gemm_kernel<<<(nrows + 63) / 64, 256, 0, stream>>>(X, Wbf, Xp, nrows);

    if (ws_size >= need && nbuck <= NBMAX) {
        int*  gcnt   = (int*)((char*)d_ws + off_gc);
        int*  starts = (int*)((char*)d_ws + off_st);
        int*  cursor = (int*)((char*)d_ws + off_cu);
        int2* binned = (int2*)((char*)d_ws + off_bn);

        hipMemsetAsync(gcnt, 0, (size_t)NBMAX * 4, stream);
        bhist_kernel<<<nchunks, 256, 0, stream>>>(L_rows, gcnt, nnz, nbuck);
        bscan_kernel<<<1, SCAN_BS, 0, stream>>>(gcnt, starts, cursor, nbuck);
        binning_kernel<<<nchunks, 256, 0, stream>>>(L_rows, L_cols, L_vals,
                                                    cursor, binned, nnz, nbuck);
        spmm_bucket_kernel<<<nbuck, 256, 0, stream>>>(starts, cursor, binned,
                                                      Xp, out, nrows);
    } else {
        hipMemsetAsync(d_out, 0, (size_t)out_size * sizeof(float), stream);
        long long total = (long long)nnz * 64;
        spmm_atomic_kernel<<<(int)((total + 255) / 256), 256, 0, stream>>>(
            L_rows, L_cols, L_vals, Xp, out, nnz);
    }
}

// Round 6
// 453.902 us; speedup vs baseline: 2.0160x; 2.0160x over previous
//
#include <hip/hip_runtime.h>

#define N_IN_CH 256
#define N_OUT_CH 64
#define SCAN_BS 1024

typedef __attribute__((ext_vector_type(8))) short short8;
typedef __attribute__((ext_vector_type(4))) float f32x4;

__device__ inline ushort f2bf(float f) {
    unsigned u = __float_as_uint(f);
    return (ushort)((u + 0x7FFFu + ((u >> 16) & 1u)) >> 16);   // RTNE
}
__device__ inline float bf2f(ushort u) {
    return __uint_as_float(((unsigned)u) << 16);
}

// --- Kernel 1: W [64][256] fp32 -> bf16 ---
__global__ void wbf_kernel(const float* __restrict__ W, ushort* __restrict__ Wbf) {
    int i = blockIdx.x * blockDim.x + threadIdx.x;
    if (i < N_OUT_CH * N_IN_CH) Wbf[i] = f2bf(W[i]);
}

// --- Kernel 2: Xp = X @ W^T via bf16 MFMA, direct-to-register (no staging LDS).
// Each wave computes 16 rows x 64 cols, K=256 unrolled (8 MFMA k-steps x 4 n-tiles).
// A-frag: lane(ml,quad) holds A[m=ml][k=quad*8..+8] = 16B contiguous -> direct
// global loads (fp32, converted in-reg). B-frag from 32KB L2-hot Wbf.
__global__ __launch_bounds__(256) void mfma_gemm_kernel(const float* __restrict__ X,
        const ushort* __restrict__ Wbf, ushort* __restrict__ Xp, int nrows) {
    __shared__ ushort so[64 * N_OUT_CH];    // 8 KB epilogue repack

    const int tid = threadIdx.x;
    const int wave = tid >> 6, lane = tid & 63;
    const int ml = lane & 15, quad = lane >> 4;
    const int row0 = blockIdx.x * 64;
    const int arow = row0 + wave * 16 + ml;
    const bool rv = arow < nrows;

    const float* xr = X + (size_t)(rv ? arow : 0) * N_IN_CH + quad * 8;

    // Load A: 8 k-tiles x 8 fp32 each, convert to bf16 in registers
    short8 a[8];
    #pragma unroll
    for (int kt = 0; kt < 8; ++kt) {
        float4 lo = make_float4(0.f, 0.f, 0.f, 0.f), hi = lo;
        if (rv) {
            lo = *(const float4*)&xr[kt * 32];
            hi = *(const float4*)&xr[kt * 32 + 4];
        }
        short8 t;
        t[0] = (short)f2bf(lo.x); t[1] = (short)f2bf(lo.y);
        t[2] = (short)f2bf(lo.z); t[3] = (short)f2bf(lo.w);
        t[4] = (short)f2bf(hi.x); t[5] = (short)f2bf(hi.y);
        t[6] = (short)f2bf(hi.z); t[7] = (short)f2bf(hi.w);
        a[kt] = t;
    }

    // B base: lane(ml,quad) reads W[nt*16+ml][quad*8 + kt*32 .. +8]
    const ushort* wb = Wbf + (size_t)ml * N_IN_CH + quad * 8;

    f32x4 acc[4];
    #pragma unroll
    for (int nt = 0; nt < 4; ++nt) acc[nt] = (f32x4){0.f, 0.f, 0.f, 0.f};

    #pragma unroll
    for (int kt = 0; kt < 8; ++kt) {
        #pragma unroll
        for (int nt = 0; nt < 4; ++nt) {
            short8 b = *(const short8*)&wb[nt * 16 * N_IN_CH + kt * 32];
            acc[nt] = __builtin_amdgcn_mfma_f32_16x16x32_bf16(a[kt], b, acc[nt], 0, 0, 0);
        }
    }

    // Epilogue: C/D col=ml, row=quad*4+reg -> LDS -> coalesced ushort4 stores
    #pragma unroll
    for (int nt = 0; nt < 4; ++nt)
        #pragma unroll
        for (int reg = 0; reg < 4; ++reg)
            so[(wave * 16 + quad * 4 + reg) * N_OUT_CH + nt * 16 + ml] = f2bf(acc[nt][reg]);
    __syncthreads();

    #pragma unroll
    for (int it = 0; it < 4; ++it) {
        int f = it * 256 + tid;        // ushort4 slot: 64 rows x 16 slots
        int r = f >> 4, c4 = f & 15;
        int gr = row0 + r;
        if (gr < nrows)
            *(ushort4*)&Xp[(size_t)gr * N_OUT_CH + c4 * 4] = *(ushort4*)&so[r * N_OUT_CH + c4 * 4];
    }
}

// --- CSR build phase (round-4 proven path) ---
__global__ void hist_kernel(const int* __restrict__ rows, int* __restrict__ cnt, int nnz) {
    int e = blockIdx.x * blockDim.x + threadIdx.x;
    if (e < nnz) atomicAdd(&cnt[rows[e]], 1);
}

__global__ __launch_bounds__(SCAN_BS) void scan1_kernel(const int* __restrict__ c,
        int* __restrict__ bsum, int n) {
    __shared__ int sd[SCAN_BS / 64];
    int i = blockIdx.x * SCAN_BS + threadIdx.x;
    int v = (i < n) ? c[i] : 0;
    #pragma unroll
    for (int d = 32; d > 0; d >>= 1) v += __shfl_down(v, d, 64);
    if ((threadIdx.x & 63) == 0) sd[threadIdx.x >> 6] = v;
    __syncthreads();
    if (threadIdx.x < SCAN_BS / 64) {
        int s = sd[threadIdx.x];
        #pragma unroll
        for (int d = SCAN_BS / 128; d > 0; d >>= 1) s += __shfl_down(s, d, 64);
        if (threadIdx.x == 0) bsum[blockIdx.x] = s;
    }
}

__global__ __launch_bounds__(SCAN_BS) void scan2_kernel(int* __restrict__ bsum, int nb) {
    __shared__ int sh[SCAN_BS];
    int t = threadIdx.x;
    int v = (t < nb) ? bsum[t] : 0;
    sh[t] = v;
    __syncthreads();
    for (int d = 1; d < SCAN_BS; d <<= 1) {
        int u = (t >= d) ? sh[t - d] : 0;
        __syncthreads();
        sh[t] += u;
        __syncthreads();
    }
    if (t < nb) bsum[t] = sh[t] - v;   // exclusive
}

__global__ __launch_bounds__(SCAN_BS) void scan3_kernel(int* __restrict__ c,
        const int* __restrict__ bsum, int n) {
    __shared__ int sh[SCAN_BS];
    int i = blockIdx.x * SCAN_BS + threadIdx.x;
    int t = threadIdx.x;
    int v = (i < n) ? c[i] : 0;
    sh[t] = v;
    __syncthreads();
    for (int d = 1; d < SCAN_BS; d <<= 1) {
        int u = (t >= d) ? sh[t - d] : 0;
        __syncthreads();
        sh[t] += u;
        __syncthreads();
    }
    if (i < n) c[i] = sh[t] - v + bsum[blockIdx.x];
}

__global__ void scatter_kernel(const int* __restrict__ rows, const int* __restrict__ cols,
        const float* __restrict__ vals, int* __restrict__ starts,
        int2* __restrict__ colval, int nnz) {
    int e = blockIdx.x * blockDim.x + threadIdx.x;
    if (e < nnz) {
        int r = rows[e];
        int pos = atomicAdd(&starts[r], 1);
        int2 cv;
        cv.x = cols[e];
        cv.y = __float_as_int(vals[e]);
        colval[pos] = cv;
    }
}

// --- Kernel 3: CSR SpMM, one wave per row, bf16 gathers, unroll-4 ---
__global__ __launch_bounds__(256) void spmm_csr_kernel(const int* __restrict__ ends,
        const int2* __restrict__ colval, const ushort* __restrict__ Xp,
        float* __restrict__ out, int nrows) {
    int t = blockIdx.x * blockDim.x + threadIdx.x;
    int row = t >> 6;
    int lane = t & 63;
    if (row >= nrows) return;
    int start = (row == 0) ? 0 : ends[row - 1];
    int end = ends[row];
    float a0 = 0.f, a1 = 0.f, a2 = 0.f, a3 = 0.f;
    int i = start;
    for (; i + 4 <= end; i += 4) {
        int2 c0 = colval[i], c1 = colval[i + 1], c2 = colval[i + 2], c3 = colval[i + 3];
        float x0 = bf2f(Xp[(size_t)c0.x * N_OUT_CH + lane]);
        float x1 = bf2f(Xp[(size_t)c1.x * N_OUT_CH + lane]);
        float x2 = bf2f(Xp[(size_t)c2.x * N_OUT_CH + lane]);
        float x3 = bf2f(Xp[(size_t)c3.x * N_OUT_CH + lane]);
        a0 += __int_as_float(c0.y) * x0;
        a1 += __int_as_float(c1.y) * x1;
        a2 += __int_as_float(c2.y) * x2;
        a3 += __int_as_float(c3.y) * x3;
    }
    for (; i < end; ++i) {
        int2 cv = colval[i];
        a0 += __int_as_float(cv.y) * bf2f(Xp[(size_t)cv.x * N_OUT_CH + lane]);
    }
    out[(size_t)row * N_OUT_CH + lane] = (a0 + a1) + (a2 + a3);
}

// --- Fallback atomic SpMM (ws too small — not expected) ---
__global__ __launch_bounds__(256) void spmm_atomic_kernel(const int* __restrict__ rows,
        const int* __restrict__ cols, const float* __restrict__ vals,
        const ushort* __restrict__ Xp, float* __restrict__ out, int nnz) {
    int t = blockIdx.x * blockDim.x + threadIdx.x;
    int e = t >> 6;
    int c = t & 63;
    if (e < nnz) {
        atomicAdd(&out[(size_t)rows[e] * N_OUT_CH + c],
                  vals[e] * bf2f(Xp[(size_t)cols[e] * N_OUT_CH + c]));
    }
}

extern "C" void kernel_launch(void* const* d_in, const int* in_sizes, int n_in,
                              void* d_out, int out_size, void* d_ws, size_t ws_size,
                              hipStream_t stream) {
    const float* X      = (const float*)d_in[2];
    const float* W      = (const float*)d_in[3];
    const int*   L_rows = (const int*)d_in[4];
    const int*   L_cols = (const int*)d_in[5];
    const float* L_vals = (const float*)d_in[6];
    float* out = (float*)d_out;

    const int nrows = in_sizes[2] / N_IN_CH;   // 100000
    const int nnz   = in_sizes[4];             // 1600000

    const int nb_scan = (nrows + SCAN_BS - 1) / SCAN_BS;

    // workspace layout (8B-aligned)
    size_t off_wbf = 0;                                          // 32 KB
    size_t off_xp  = 65536;
    size_t off_st  = off_xp + (size_t)nrows * N_OUT_CH * 2;      // Xp bf16: 12.8 MB
    size_t off_bs  = off_st + ((size_t)nrows * 4 + 7) / 8 * 8;   // starts: 400 KB
    size_t off_cv  = off_bs + ((size_t)nb_scan * 4 + 7) / 8 * 8;
    size_t need    = off_cv + (size_t)nnz * 8;                   // colval: 12.8 MB

    ushort* Wbf = (ushort*)((char*)d_ws + off_wbf);
    ushort* Xp  = (ushort*)((char*)d_ws + off_xp);

    wbf_kernel<<<(N_OUT_CH * N_IN_CH + 255) / 256, 256, 0, stream>>>(W, Wbf);
    mfma_gemm_kernel<<<(nrows + 63) / 64, 256, 0, stream>>>(X, Wbf, Xp, nrows);

    if (ws_size >= need) {
        int*  starts = (int*)((char*)d_ws + off_st);
        int*  bsum   = (int*)((char*)d_ws + off_bs);
        int2* colval = (int2*)((char*)d_ws + off_cv);

        hipMemsetAsync(starts, 0, (size_t)nrows * 4, stream);
        hist_kernel<<<(nnz + 255) / 256, 256, 0, stream>>>(L_rows, starts, nnz);
        scan1_kernel<<<nb_scan, SCAN_BS, 0, stream>>>(starts, bsum, nrows);
        scan2_kernel<<<1, SCAN_BS, 0, stream>>>(bsum, nb_scan);
        scan3_kernel<<<nb_scan, SCAN_BS, 0, stream>>>(starts, bsum, nrows);
        scatter_kernel<<<(nnz + 255) / 256, 256, 0, stream>>>(L_rows, L_cols, L_vals,
                                                              starts, colval, nnz);
        long long total = (long long)nrows * 64;
        spmm_csr_kernel<<<(int)((total + 255) / 256), 256, 0, stream>>>(starts, colval,
                                                                        Xp, out, nrows);
    } else {
        hipMemsetAsync(d_out, 0, (size_t)out_size * sizeof(float), stream);
        long long total = (long long)nnz * 64;
        spmm_atomic_kernel<<<(int)((total + 255) / 256), 256, 0, stream>>>(
            L_rows, L_cols, L_vals, Xp, out, nnz);
    }
}